// Round 7
// baseline (319.733 us; speedup 1.0000x reference)
//
#include <hip/hip_runtime.h>
#include <stdint.h>

#define B_ 4
#define T_ 2048
#define C_ 1024
#define H_ 16
#define HD 64

typedef __attribute__((ext_vector_type(8))) short bf16x8;
typedef __attribute__((ext_vector_type(4))) short bf16x4;
typedef __attribute__((ext_vector_type(4))) float v4f;
typedef __attribute__((ext_vector_type(4))) uint32_t v4u;

static __device__ __forceinline__ short f2bf(float f) {
    union { float f; uint32_t u; } v; v.f = f;
    uint32_t u = v.u;
    uint32_t r = (u + 0x7fffu + ((u >> 16) & 1u)) >> 16;
    return (short)(r & 0xffffu);
}
// round-half-up bf16 pack of 2 fp32 -> 1 dword (lo short = x). 3 VALU ops.
static __device__ __forceinline__ uint32_t pack2(float x, float y) {
    uint32_t a = __float_as_uint(x) + 0x8000u;
    uint32_t b = __float_as_uint(y) + 0x8000u;
    return __builtin_amdgcn_perm(b, a, 0x07060302u);  // [a.b2,a.b3,b.b2,b.b3]
}
// trunc bf16 pack of 2 fp32 -> 1 dword (lo short = x). 1 VALU op.
static __device__ __forceinline__ uint32_t pack2t(float x, float y) {
    return __builtin_amdgcn_perm(__float_as_uint(y), __float_as_uint(x), 0x07060302u);
}
static __device__ __forceinline__ void gload_lds16(const void* g, void* l) {
    __builtin_amdgcn_global_load_lds(
        (const __attribute__((address_space(1))) void*)g,
        (__attribute__((address_space(3))) void*)l, 16, 0, 0);
}

// Bulk fp32->bf16: xq,xk (4096 blocks each) + 4 weights (512 blocks each).
__global__ __launch_bounds__(256) void convx(
    const float* __restrict__ x0, const float* __restrict__ x1,
    short* __restrict__ o0, short* __restrict__ o1,
    const float* __restrict__ w0, const float* __restrict__ w1,
    const float* __restrict__ w2, const float* __restrict__ w3,
    short* __restrict__ wout)
{
    int bid = blockIdx.x;
    const float* src; short* dst; size_t id;
    if (bid < 8192) {
        src = (bid < 4096) ? x0 : x1;
        dst = (bid < 4096) ? o0 : o1;
        id = (size_t)(bid & 4095) * 256 + threadIdx.x;
    } else {
        int wb = bid - 8192;
        int wi = wb >> 9;
        src = (wi == 0) ? w0 : (wi == 1) ? w1 : (wi == 2) ? w2 : w3;
        dst = wout + (size_t)wi * (C_ * C_);
        id = (size_t)(wb & 511) * 256 + threadIdx.x;
    }
    const float* p = src + id * 8;
    v4f a0 = *(const v4f*)p, a1 = *(const v4f*)(p + 4);
    v4u dv;
    dv[0] = pack2(a0[0], a0[1]); dv[1] = pack2(a0[2], a0[3]);
    dv[2] = pack2(a1[0], a1[1]); dv[3] = pack2(a1[2], a1[3]);
    *(v4u*)&dst[id * 8] = dv;
}

// ---- XOR LDS swizzle, BK=64 (8 chunks of 16B per 128B row) ----
// LDS[row][ch] = G[row][ch ^ (row&7)]; gll src chunk (l&7)^(l>>3) (rule 21);
// frag read chunk (4s+g)^(c&7). Verified 0 SQ_LDS_BANK_CONFLICT (R2/R4).
//
// ---- Counted 2-phase pipeline (T3 minimal recipe, m248v2) ----
// prologue: STAGE(buf0,t0); vmcnt(0); s_barrier
// per tile: STAGE(buf^1, t+1)              [issue-early]
//           compute(buf)                   [stage latency hides HERE]
//           (z2: pack+ds_write buf^1)      [write-late, T14]
//           asm vmcnt(0) lgkmcnt(0); s_barrier   [drain AFTER compute]
// KEY vs R3's failed dbuf: raw s_barrier + asm waitcnt (not __syncthreads,
// whose vmcnt(0) drains BEFORE compute), and static buffers via x2 unroll
// (no dynamic LDS indexing). One barrier per tile. LDS 64KB -> 2 blocks/CU;
// latency hiding is now in-wave so reduced TLP is acceptable (m132's BK128
// regression was the drain-style structure where only TLP hides latency).

// Fused QKV projection, 128x128 tile, 4 waves 2x2, K=1024, BK=64. Grid (64,8,3).
// z=0: Q = xq_bf @ Wq^T -> bf16 (b,h,t,d) * qscale
// z=1: K = xk_bf @ Wk^T -> bf16 (b,h,t,d)
// z=2: V^T: A = Wv bf16 (gll), B = xv fp32 (reg-load early, pack+write late)
__global__ __launch_bounds__(256) void proj_gemm(
    const short* __restrict__ Xq, const short* __restrict__ Xk,
    const short* __restrict__ Wb, const float* __restrict__ xv,
    short* __restrict__ Qh, short* __restrict__ Kh, short* __restrict__ Vt,
    float qscale)
{
    const int K = 1024;
    __shared__ short As[2][128 * 64];
    __shared__ short Bs[2][128 * 64];
    const int t = threadIdx.x;
    const int w = t >> 6, l = t & 63, g = l >> 4, c = l & 15;
    const int wm = w & 1, wn = w >> 1;
    const int z = blockIdx.z;
    const int m0 = (z == 2 ? blockIdx.y : blockIdx.x) * 128;
    const int n0 = (z == 2 ? blockIdx.x : blockIdx.y) * 128;
    const short* Ab = (z == 0) ? Xq : (z == 1) ? Xk : (Wb + 2 * C_ * C_);
    const short* Bb = (z == 0) ? Wb : (Wb + C_ * C_);
    const short* Agb = Ab + (size_t)m0 * K;
    const short* Bgb = Bb + (size_t)n0 * K;

    const int srow = l >> 3;               // row-in-8 for gll
    const int sch = (l & 7) ^ (l >> 3);    // swizzled source chunk (0..7)
    const int rch = c & 7;                 // row bits for frag-read swizzle

    v4f acc[4][4];
#pragma unroll
    for (int i = 0; i < 4; ++i)
#pragma unroll
        for (int j = 0; j < 4; ++j) acc[i][j] = (v4f){0.f, 0.f, 0.f, 0.f};

    v4f pb0[4], pb1[4];  // z==2 in-flight xv registers

    auto stage4 = [&](short* dst, const short* gbase, int kk) {
#pragma unroll
        for (int i = 0; i < 4; ++i) {
            int sp = w * 4 + i;
            gload_lds16(gbase + (size_t)(sp * 8 + srow) * K + kk + sch * 8,
                        dst + sp * 512);
        }
    };
    auto loadB = [&](int kk) {
#pragma unroll
        for (int i = 0; i < 4; ++i) {
            int id = i * 256 + t;
            int rr = id >> 3, cc = id & 7;
            const float* pp = xv + (size_t)(n0 + rr) * K + kk + cc * 8;
            pb0[i] = *(const v4f*)pp;
            pb1[i] = *(const v4f*)(pp + 4);
        }
    };
    auto packB = [&](short* bsb) {
#pragma unroll
        for (int i = 0; i < 4; ++i) {
            int id = i * 256 + t;
            int rr = id >> 3, cc = id & 7;
            v4u dv;
            dv[0] = pack2(pb0[i][0], pb0[i][1]); dv[1] = pack2(pb0[i][2], pb0[i][3]);
            dv[2] = pack2(pb1[i][0], pb1[i][1]); dv[3] = pack2(pb1[i][2], pb1[i][3]);
            *(v4u*)&bsb[rr * 64 + ((cc ^ (rr & 7)) * 8)] = dv;
        }
    };
    auto compute = [&](const short* asb, const short* bsb) {
#pragma unroll
        for (int s = 0; s < 2; ++s) {
            const int kch = ((4 * s + g) ^ rch) * 8;
            bf16x8 af[4], bfr[4];
#pragma unroll
            for (int i = 0; i < 4; ++i)
                af[i] = *(const bf16x8*)&asb[(wm * 64 + i * 16 + c) * 64 + kch];
#pragma unroll
            for (int j = 0; j < 4; ++j)
                bfr[j] = *(const bf16x8*)&bsb[(wn * 64 + j * 16 + c) * 64 + kch];
#pragma unroll
            for (int i = 0; i < 4; ++i)
#pragma unroll
                for (int j = 0; j < 4; ++j)
                    acc[i][j] = __builtin_amdgcn_mfma_f32_16x16x32_bf16(af[i], bfr[j], acc[i][j], 0, 0, 0);
        }
    };

    // ---- prologue: tile 0 -> buffer 0 ----
    if (z < 2) {
        stage4(&As[0][0], Agb, 0);
        stage4(&Bs[0][0], Bgb, 0);
    } else {
        loadB(0);
        stage4(&As[0][0], Agb, 0);
        packB(&Bs[0][0]);            // compiler waits on the xv loads
    }
    asm volatile("s_waitcnt vmcnt(0) lgkmcnt(0)" ::: "memory");
    __builtin_amdgcn_s_barrier();

    for (int k0 = 0; k0 < K; k0 += 128) {
        // -------- tile k0 (buf 0), prefetch k0+64 (buf 1) — always exists
        if (z < 2) {
            stage4(&As[1][0], Agb, k0 + 64);
            stage4(&Bs[1][0], Bgb, k0 + 64);
        } else {
            loadB(k0 + 64);
            stage4(&As[1][0], Agb, k0 + 64);
        }
        compute(&As[0][0], &Bs[0][0]);
        if (z == 2) packB(&Bs[1][0]);
        asm volatile("s_waitcnt vmcnt(0) lgkmcnt(0)" ::: "memory");
        __builtin_amdgcn_s_barrier();
        // -------- tile k0+64 (buf 1), prefetch k0+128 (buf 0) if it exists
        const bool pre = (k0 + 128 < K);
        if (pre) {
            if (z < 2) {
                stage4(&As[0][0], Agb, k0 + 128);
                stage4(&Bs[0][0], Bgb, k0 + 128);
            } else {
                loadB(k0 + 128);
                stage4(&As[0][0], Agb, k0 + 128);
            }
        }
        compute(&As[1][0], &Bs[1][0]);
        if (pre && z == 2) packB(&Bs[0][0]);
        asm volatile("s_waitcnt vmcnt(0) lgkmcnt(0)" ::: "memory");
        __builtin_amdgcn_s_barrier();
    }

    // C/D: col = lane&15, row = (lane>>4)*4 + reg  [m89/m91]
    if (z < 2) {
        short* Out = (z == 0) ? Qh : Kh;
        const float os = (z == 0) ? qscale : 1.0f;
#pragma unroll
        for (int i = 0; i < 4; ++i)
#pragma unroll
            for (int j = 0; j < 4; ++j)
#pragma unroll
                for (int r = 0; r < 4; ++r) {
                    int m = m0 + wm * 64 + i * 16 + g * 4 + r;   // token
                    int n = n0 + wn * 64 + j * 16 + c;           // feature
                    int b = m >> 11, tt = m & (T_ - 1);
                    int h = n >> 6, d = n & 63;
                    Out[((size_t)(b * H_ + h) * T_ + tt) * HD + d] = f2bf(acc[i][j][r] * os);
                }
    } else {
#pragma unroll
        for (int i = 0; i < 4; ++i)
#pragma unroll
            for (int j = 0; j < 4; ++j)
#pragma unroll
                for (int r = 0; r < 4; ++r) {
                    int m = m0 + wm * 64 + i * 16 + g * 4 + r;   // feature
                    int n = n0 + wn * 64 + j * 16 + c;           // token
                    int b = n >> 11, tt = n & (T_ - 1);
                    int h = m >> 6, d = m & 63;
                    Vt[((size_t)(b * H_ + h) * HD + d) * T_ + tt] = f2bf(acc[i][j][r]);
                }
    }
}

// Output projection: Y bf16 @ Wo^T + bo -> fp32 row-major. Grid (64,8). BK=64,
// counted 2-phase pipeline (same structure as proj_gemm z<2).
__global__ __launch_bounds__(256) void gemm_o(
    const short* __restrict__ Yb, const short* __restrict__ Wo,
    float* __restrict__ Out, const float* __restrict__ bias)
{
    const int K = 1024;
    __shared__ short As[2][128 * 64];
    __shared__ short Bs[2][128 * 64];
    const int t = threadIdx.x;
    const int w = t >> 6, l = t & 63, g = l >> 4, c = l & 15;
    const int wm = w & 1, wn = w >> 1;
    const int m0 = blockIdx.x * 128, n0 = blockIdx.y * 128;
    const short* Agb = Yb + (size_t)m0 * K;
    const short* Bgb = Wo + (size_t)n0 * K;

    const int srow = l >> 3;
    const int sch = (l & 7) ^ (l >> 3);
    const int rch = c & 7;

    v4f acc[4][4];
#pragma unroll
    for (int i = 0; i < 4; ++i)
#pragma unroll
        for (int j = 0; j < 4; ++j) acc[i][j] = (v4f){0.f, 0.f, 0.f, 0.f};

    auto stage4 = [&](short* dst, const short* gbase, int kk) {
#pragma unroll
        for (int i = 0; i < 4; ++i) {
            int sp = w * 4 + i;
            gload_lds16(gbase + (size_t)(sp * 8 + srow) * K + kk + sch * 8,
                        dst + sp * 512);
        }
    };
    auto compute = [&](const short* asb, const short* bsb) {
#pragma unroll
        for (int s = 0; s < 2; ++s) {
            const int kch = ((4 * s + g) ^ rch) * 8;
            bf16x8 af[4], bfr[4];
#pragma unroll
            for (int i = 0; i < 4; ++i)
                af[i] = *(const bf16x8*)&asb[(wm * 64 + i * 16 + c) * 64 + kch];
#pragma unroll
            for (int j = 0; j < 4; ++j)
                bfr[j] = *(const bf16x8*)&bsb[(wn * 64 + j * 16 + c) * 64 + kch];
#pragma unroll
            for (int i = 0; i < 4; ++i)
#pragma unroll
                for (int j = 0; j < 4; ++j)
                    acc[i][j] = __builtin_amdgcn_mfma_f32_16x16x32_bf16(af[i], bfr[j], acc[i][j], 0, 0, 0);
        }
    };

    stage4(&As[0][0], Agb, 0);
    stage4(&Bs[0][0], Bgb, 0);
    asm volatile("s_waitcnt vmcnt(0) lgkmcnt(0)" ::: "memory");
    __builtin_amdgcn_s_barrier();

    for (int k0 = 0; k0 < K; k0 += 128) {
        stage4(&As[1][0], Agb, k0 + 64);
        stage4(&Bs[1][0], Bgb, k0 + 64);
        compute(&As[0][0], &Bs[0][0]);
        asm volatile("s_waitcnt vmcnt(0) lgkmcnt(0)" ::: "memory");
        __builtin_amdgcn_s_barrier();
        const bool pre = (k0 + 128 < K);
        if (pre) {
            stage4(&As[0][0], Agb, k0 + 128);
            stage4(&Bs[0][0], Bgb, k0 + 128);
        }
        compute(&As[1][0], &Bs[1][0]);
        asm volatile("s_waitcnt vmcnt(0) lgkmcnt(0)" ::: "memory");
        __builtin_amdgcn_s_barrier();
    }

#pragma unroll
    for (int i = 0; i < 4; ++i)
#pragma unroll
        for (int j = 0; j < 4; ++j)
#pragma unroll
            for (int r = 0; r < 4; ++r) {
                int m = m0 + wm * 64 + i * 16 + g * 4 + r;
                int n = n0 + wn * 64 + j * 16 + c;
                Out[(size_t)m * C_ + n] = acc[i][j][r] + bias[n];
            }
}

// Flash attention, causal, no-rescale softmax (Q pre-scaled by log2(e)/8).
// Q,K: (B,H,T,64) bf16; Vt: (B,H,64,T) bf16; Y: (B,T,C) bf16.
// Swapped QK^T keeps P fully in-register; Ks XOR-swizzled (conflicts=0).
// MERGED q-tile pair {qtL=p, qtH=31-p}, fused PV (V-frag read once feeds
// both tiles — R6: dropped attn out of top-5). UNCHANGED from R6.
__global__ __launch_bounds__(256) void attn_kernel(
    const short* __restrict__ Q, const short* __restrict__ Kp,
    const short* __restrict__ Vt, short* __restrict__ Y)
{
    __shared__ short Ks[2 * 64 * 32];    // [dim-half][key][32] via gll (swizzled)
    __shared__ short Vs[64 * 72];        // [d][key] pad 72
    const int t = threadIdx.x;
    const int w = t >> 6, l = t & 63, g = l >> 4, c = l & 15;
    const int bid = blockIdx.x;          // 1024 blocks
    const int slot = bid >> 3;
    const int p = slot & 15;
    const size_t bh = (size_t)((bid & 7) * 8 + (slot >> 4));  // XCD-local bh

    const int srow = l >> 2;
    const int sch = (l & 3) ^ ((l >> 3) & 3);
    const int gs = (g ^ ((c >> 1) & 3)) * 8;

    bf16x8 ones;
#pragma unroll
    for (int i = 0; i < 8; ++i) ones[i] = (short)0x3F80;  // bf16 1.0

    const int qtL = p, qtH = 31 - p;     // qtL <= 15 < 16 <= qtH always
    const int qbL = qtL * 64, qbH = qtH * 64;

    bf16x8 qL0, qL1, qH0, qH1;   // pre-scaled Q fragments (q = qb + w*16 + c)
    {
        const short* qp = &Q[(bh * T_ + qbL + w * 16 + c) * HD + g * 8];
        qL0 = *(const bf16x8*)qp;
        qL1 = *(const bf16x8*)(qp + 32);
    }
    {
        const short* qp = &Q[(bh * T_ + qbH + w * 16 + c) * HD + g * 8];
        qH0 = *(const bf16x8*)qp;
        qH1 = *(const bf16x8*)(qp + 32);
    }

    v4f OL[4], OH[4], accL, accH;
    accL = (v4f){0.f, 0.f, 0.f, 0.f};
    accH = (v4f){0.f, 0.f, 0.f, 0.f};
#pragma unroll
    for (int d = 0; d < 4; ++d) {
        OL[d] = (v4f){0.f, 0.f, 0.f, 0.f};
        OH[d] = (v4f){0.f, 0.f, 0.f, 0.f};
    }

    union pu { bf16x8 v; uint32_t u[4]; };

    for (int kb = 0; kb <= qtH; ++kb) {
        const int kbase = kb * 64;
        __syncthreads();
        // K tile via gll: 8 chunks (half,rowblk), 2 per wave, swizzled src
#pragma unroll
        for (int i = 0; i < 2; ++i) {
            int gi = w * 2 + i;
            int hk = gi >> 2, rb = gi & 3;
            const short* gp = &Kp[(bh * T_ + kbase + rb * 16 + srow) * HD + hk * 32 + sch * 8];
            gload_lds16(gp, &Ks[hk * 2048 + rb * 512]);
        }
        // V tile (transposed layout) via VGPR, padded rows
#pragma unroll
        for (int i = 0; i < 2; ++i) {
            int id = i * 256 + t;
            int rr = id >> 3, cc = id & 7;
            *(bf16x8*)&Vs[rr * 72 + cc * 8] =
                *(const bf16x8*)&Vt[(bh * HD + rr) * T_ + kbase + cc * 8];
        }
        __syncthreads();

        const bool doL = (kb <= qtL);   // wave-uniform

        // ---- QK^T high (kf frags read inline; transient regs) ----
        pu paH[2], paL[2];
        {
            float s2[4][4];
#pragma unroll
            for (int j = 0; j < 4; ++j) {
                bf16x8 kf0 = *(const bf16x8*)&Ks[(j * 16 + c) * 32 + gs];
                bf16x8 kf1 = *(const bf16x8*)&Ks[2048 + (j * 16 + c) * 32 + gs];
                v4f sa = (v4f){0.f, 0.f, 0.f, 0.f};
                sa = __builtin_amdgcn_mfma_f32_16x16x32_bf16(kf0, qH0, sa, 0, 0, 0);
                sa = __builtin_amdgcn_mfma_f32_16x16x32_bf16(kf1, qH1, sa, 0, 0, 0);
#pragma unroll
                for (int r = 0; r < 4; ++r) s2[j][r] = sa[r];
            }
            if (kb == qtH) {  // diagonal tile mask
                const int q = qbH + w * 16 + c;
#pragma unroll
                for (int j = 0; j < 4; ++j)
#pragma unroll
                    for (int r = 0; r < 4; ++r) {
                        int key = kbase + j * 16 + g * 4 + r;
                        if (key > q) s2[j][r] = -3.0e38f;
                    }
            }
#pragma unroll
            for (int s = 0; s < 2; ++s)
#pragma unroll
                for (int wi = 0; wi < 4; ++wi) {
                    int j = 2 * s + (wi >> 1);
                    int r0 = (wi & 1) * 2;
                    float x = __builtin_amdgcn_exp2f(s2[j][r0]);
                    float y = __builtin_amdgcn_exp2f(s2[j][r0 + 1]);
                    paH[s].u[wi] = pack2t(x, y);
                }
        }
        // ---- QK^T low (only while kb <= qtL) ----
        if (doL) {
            float s2[4][4];
#pragma unroll
            for (int j = 0; j < 4; ++j) {
                bf16x8 kf0 = *(const bf16x8*)&Ks[(j * 16 + c) * 32 + gs];
                bf16x8 kf1 = *(const bf16x8*)&Ks[2048 + (j * 16 + c) * 32 + gs];
                v4f sa = (v4f){0.f, 0.f, 0.f, 0.f};
                sa = __builtin_amdgcn_mfma_f32_16x16x32_bf16(kf0, qL0, sa, 0, 0, 0);
                sa = __builtin_amdgcn_mfma_f32_16x16x32_bf16(kf1, qL1, sa, 0, 0, 0);
#pragma unroll
                for (int r = 0; r < 4; ++r) s2[j][r] = sa[r];
            }
            if (kb == qtL) {  // diagonal tile mask
                const int q = qbL + w * 16 + c;
#pragma unroll
                for (int j = 0; j < 4; ++j)
#pragma unroll
                    for (int r = 0; r < 4; ++r) {
                        int key = kbase + j * 16 + g * 4 + r;
                        if (key > q) s2[j][r] = -3.0e38f;
                    }
            }
#pragma unroll
            for (int s = 0; s < 2; ++s)
#pragma unroll
                for (int wi = 0; wi < 4; ++wi) {
                    int j = 2 * s + (wi >> 1);
                    int r0 = (wi & 1) * 2;
                    float x = __builtin_amdgcn_exp2f(s2[j][r0]);
                    float y = __builtin_amdgcn_exp2f(s2[j][r0 + 1]);
                    paL[s].u[wi] = pack2t(x, y);
                }
            // ---- FUSED PV: each V-frag read once, feeds both tiles ----
#pragma unroll
            for (int s = 0; s < 2; ++s) {
#pragma unroll
                for (int d = 0; d < 4; ++d) {
                    const short* vp = &Vs[(d * 16 + c) * 72 + s * 32 + g * 4];
                    union { bf16x8 v8; bf16x4 v4[2]; } vu;
                    vu.v4[0] = *(const bf16x4*)vp;
                    vu.v4[1] = *(const bf16x4*)(vp + 16);
                    OH[d] = __builtin_amdgcn_mfma_f32_16x16x32_bf16(paH[s].v, vu.v8, OH[d], 0, 0, 0);
                    OL[d] = __builtin_amdgcn_mfma_f32_16x16x32_bf16(paL[s].v, vu.v8, OL[d], 0, 0, 0);
                }
                accH = __builtin_amdgcn_mfma_f32_16x16x32_bf16(paH[s].v, ones, accH, 0, 0, 0);
                accL = __builtin_amdgcn_mfma_f32_16x16x32_bf16(paL[s].v, ones, accL, 0, 0, 0);
            }
        } else {
            // ---- PV high only ----
#pragma unroll
            for (int s = 0; s < 2; ++s) {
#pragma unroll
                for (int d = 0; d < 4; ++d) {
                    const short* vp = &Vs[(d * 16 + c) * 72 + s * 32 + g * 4];
                    union { bf16x8 v8; bf16x4 v4[2]; } vu;
                    vu.v4[0] = *(const bf16x4*)vp;
                    vu.v4[1] = *(const bf16x4*)(vp + 16);
                    OH[d] = __builtin_amdgcn_mfma_f32_16x16x32_bf16(paH[s].v, vu.v8, OH[d], 0, 0, 0);
                }
                accH = __builtin_amdgcn_mfma_f32_16x16x32_bf16(paH[s].v, ones, accH, 0, 0, 0);
            }
        }
    }
    // D: row = q = qb+w*16+g*4+r, col = c (d-dim)
#pragma unroll
    for (int r = 0; r < 4; ++r) {
        float rlL = 1.0f / accL[r];
        float rlH = 1.0f / accH[r];
        size_t baseoff = ((size_t)(bh >> 4) * T_ + w * 16 + g * 4 + r) * C_ + (bh & 15) * HD;
        size_t offL = baseoff + (size_t)qbL * C_;
        size_t offH = baseoff + (size_t)qbH * C_;
#pragma unroll
        for (int d = 0; d < 4; ++d) {
            Y[offL + d * 16 + c] = f2bf(OL[d][r] * rlL);
            Y[offH + d * 16 + c] = f2bf(OH[d][r] * rlH);
        }
    }
}

extern "C" void kernel_launch(void* const* d_in, const int* in_sizes, int n_in,
                              void* d_out, int out_size, void* d_ws, size_t ws_size,
                              hipStream_t stream) {
    const float* xq = (const float*)d_in[0];
    const float* xk = (const float*)d_in[1];
    const float* xv = (const float*)d_in[2];
    const float* Wq = (const float*)d_in[3];
    const float* Wk = (const float*)d_in[4];
    const float* Wv = (const float*)d_in[5];
    const float* Wo = (const float*)d_in[6];
    const float* bo = (const float*)d_in[7];

    const size_t NE = (size_t)B_ * H_ * T_ * HD;   // 8.4M elems (16MB bf16)
    const size_t WE = (size_t)C_ * C_;             // 1M elems
    short* Qh    = (short*)d_ws;
    short* Kh    = Qh + NE;
    short* slotA = Kh + NE;       // xq_bf -> (after proj) Y
    short* slotB = slotA + NE;    // xk_bf
    short* Wbf   = slotB + NE;    // 4 x 2MB; total ws = 72MB
    short* Vt    = (short*)d_out; // scratch: dead until gemm_o overwrites d_out

    const float qscale = 0.18033688011112042f;     // log2(e)/sqrt(64)
    dim3 blk(256);

    hipLaunchKernelGGL(convx, dim3(10240), blk, 0, stream,
                       xq, xk, slotA, slotB, Wq, Wk, Wv, Wo, Wbf);
    hipLaunchKernelGGL(proj_gemm, dim3(64, 8, 3), blk, 0, stream,
                       slotA, slotB, Wbf, xv, Qh, Kh, Vt, qscale);
    hipLaunchKernelGGL(attn_kernel, dim3(B_ * H_ * (T_ / 128)), blk, 0, stream,
                       Qh, Kh, Vt, slotA);
    hipLaunchKernelGGL(gemm_o, dim3(64, 8), blk, 0, stream,
                       slotA, Wbf + 3 * WE, (float*)d_out, bo);
}

// Round 8
// 303.550 us; speedup vs baseline: 1.0533x; 1.0533x over previous
//
#include <hip/hip_runtime.h>
#include <stdint.h>

#define B_ 4
#define T_ 2048
#define C_ 1024
#define H_ 16
#define HD 64

typedef __attribute__((ext_vector_type(8))) short bf16x8;
typedef __attribute__((ext_vector_type(4))) short bf16x4;
typedef __attribute__((ext_vector_type(4))) float v4f;
typedef __attribute__((ext_vector_type(4))) uint32_t v4u;

static __device__ __forceinline__ short f2bf(float f) {
    union { float f; uint32_t u; } v; v.f = f;
    uint32_t u = v.u;
    uint32_t r = (u + 0x7fffu + ((u >> 16) & 1u)) >> 16;
    return (short)(r & 0xffffu);
}
// round-half-up bf16 pack of 2 fp32 -> 1 dword (lo short = x). 3 VALU ops.
static __device__ __forceinline__ uint32_t pack2(float x, float y) {
    uint32_t a = __float_as_uint(x) + 0x8000u;
    uint32_t b = __float_as_uint(y) + 0x8000u;
    return __builtin_amdgcn_perm(b, a, 0x07060302u);  // [a.b2,a.b3,b.b2,b.b3]
}
// trunc bf16 pack of 2 fp32 -> 1 dword (lo short = x). 1 VALU op.
static __device__ __forceinline__ uint32_t pack2t(float x, float y) {
    return __builtin_amdgcn_perm(__float_as_uint(y), __float_as_uint(x), 0x07060302u);
}
static __device__ __forceinline__ void gload_lds16(const void* g, void* l) {
    __builtin_amdgcn_global_load_lds(
        (const __attribute__((address_space(1))) void*)g,
        (__attribute__((address_space(3))) void*)l, 16, 0, 0);
}

// Bulk fp32->bf16: xq,xk (4096 blocks each) + 4 weights (512 blocks each).
__global__ __launch_bounds__(256) void convx(
    const float* __restrict__ x0, const float* __restrict__ x1,
    short* __restrict__ o0, short* __restrict__ o1,
    const float* __restrict__ w0, const float* __restrict__ w1,
    const float* __restrict__ w2, const float* __restrict__ w3,
    short* __restrict__ wout)
{
    int bid = blockIdx.x;
    const float* src; short* dst; size_t id;
    if (bid < 8192) {
        src = (bid < 4096) ? x0 : x1;
        dst = (bid < 4096) ? o0 : o1;
        id = (size_t)(bid & 4095) * 256 + threadIdx.x;
    } else {
        int wb = bid - 8192;
        int wi = wb >> 9;
        src = (wi == 0) ? w0 : (wi == 1) ? w1 : (wi == 2) ? w2 : w3;
        dst = wout + (size_t)wi * (C_ * C_);
        id = (size_t)(wb & 511) * 256 + threadIdx.x;
    }
    const float* p = src + id * 8;
    v4f a0 = *(const v4f*)p, a1 = *(const v4f*)(p + 4);
    v4u dv;
    dv[0] = pack2(a0[0], a0[1]); dv[1] = pack2(a0[2], a0[3]);
    dv[2] = pack2(a1[0], a1[1]); dv[3] = pack2(a1[2], a1[3]);
    *(v4u*)&dst[id * 8] = dv;
}

// ---- XOR LDS swizzle, BK=64 (8 chunks of 16B per 128B row) ----
// LDS[row][ch] = G[row][ch ^ (row&7)]; gll src chunk (l&7)^(l>>3) (rule 21);
// frag read chunk (4s+g)^(c&7). Verified 0 SQ_LDS_BANK_CONFLICT (R2/R4).
// Single-buffered, 2 barriers per K-step. R3 (__syncthreads dbuf) and R7
// (counted-vmcnt 2-phase) BOTH regressed this structure -> reverted to R4.
// The 128²/2-barrier family doesn't respond to source pipelining (m99-m141);
// escaping needs the full 8-phase 256² template (not attempted headlessly).

// Fused QKV projection, 128x128 tile, 4 waves 2x2, K=1024, BK=64. Grid (64,8,3).
// z=0: Q = xq_bf @ Wq^T -> bf16 (b,h,t,d) * qscale
// z=1: K = xk_bf @ Wk^T -> bf16 (b,h,t,d)
// z=2: V^T: A = Wv bf16, B = xv fp32 convert-stage, out bf16 (b,h,d,t)
__global__ __launch_bounds__(256) void proj_gemm(
    const short* __restrict__ Xq, const short* __restrict__ Xk,
    const short* __restrict__ Wb, const float* __restrict__ xv,
    short* __restrict__ Qh, short* __restrict__ Kh, short* __restrict__ Vt,
    float qscale)
{
    const int K = 1024;
    __shared__ short As[128 * 64];
    __shared__ short Bs[128 * 64];
    const int t = threadIdx.x;
    const int w = t >> 6, l = t & 63, g = l >> 4, c = l & 15;
    const int wm = w & 1, wn = w >> 1;
    const int z = blockIdx.z;
    const int m0 = (z == 2 ? blockIdx.y : blockIdx.x) * 128;
    const int n0 = (z == 2 ? blockIdx.x : blockIdx.y) * 128;
    const short* Ab = (z == 0) ? Xq : (z == 1) ? Xk : (Wb + 2 * C_ * C_);
    const short* Bb = (z == 0) ? Wb : (Wb + C_ * C_);

    const int srow = l >> 3;               // row-in-8 for gll
    const int sch = (l & 7) ^ (l >> 3);    // swizzled source chunk (0..7)
    const int rch = c & 7;                 // row bits for frag-read swizzle

    v4f acc[4][4];
#pragma unroll
    for (int i = 0; i < 4; ++i)
#pragma unroll
        for (int j = 0; j < 4; ++j) acc[i][j] = (v4f){0.f, 0.f, 0.f, 0.f};

    for (int k0 = 0; k0 < K; k0 += 64) {
        __syncthreads();
        // A via gll: 16 spans of 8 rows, 4 per wave
#pragma unroll
        for (int i = 0; i < 4; ++i) {
            int sp = w * 4 + i;
            gload_lds16(Ab + (size_t)(m0 + sp * 8 + srow) * K + k0 + sch * 8,
                        &As[sp * 512]);
        }
        if (z < 2) {                        // B via gll (weights)
#pragma unroll
            for (int i = 0; i < 4; ++i) {
                int sp = w * 4 + i;
                gload_lds16(Bb + (size_t)(n0 + sp * 8 + srow) * K + k0 + sch * 8,
                            &Bs[sp * 512]);
            }
        } else {                            // B fp32 convert-stage (xv)
#pragma unroll
            for (int i = 0; i < 4; ++i) {
                int id = i * 256 + t;       // 0..1023
                int rr = id >> 3, cc = id & 7;
                const float* p = xv + (size_t)(n0 + rr) * K + k0 + cc * 8;
                v4f a0 = *(const v4f*)p, a1 = *(const v4f*)(p + 4);
                v4u dv;
                dv[0] = pack2(a0[0], a0[1]); dv[1] = pack2(a0[2], a0[3]);
                dv[2] = pack2(a1[0], a1[1]); dv[3] = pack2(a1[2], a1[3]);
                *(v4u*)&Bs[rr * 64 + ((cc ^ (rr & 7)) * 8)] = dv;
            }
        }
        __syncthreads();
        // 2 k-slices of 32; fragments read per slice to keep VGPRs flat
#pragma unroll
        for (int s = 0; s < 2; ++s) {
            const int kch = ((4 * s + g) ^ rch) * 8;
            bf16x8 af[4], bfr[4];
#pragma unroll
            for (int i = 0; i < 4; ++i)
                af[i] = *(const bf16x8*)&As[(wm * 64 + i * 16 + c) * 64 + kch];
#pragma unroll
            for (int j = 0; j < 4; ++j)
                bfr[j] = *(const bf16x8*)&Bs[(wn * 64 + j * 16 + c) * 64 + kch];
#pragma unroll
            for (int i = 0; i < 4; ++i)
#pragma unroll
                for (int j = 0; j < 4; ++j)
                    acc[i][j] = __builtin_amdgcn_mfma_f32_16x16x32_bf16(af[i], bfr[j], acc[i][j], 0, 0, 0);
        }
    }
    // C/D: col = lane&15, row = (lane>>4)*4 + reg  [m89/m91]
    if (z < 2) {
        short* Out = (z == 0) ? Qh : Kh;
        const float os = (z == 0) ? qscale : 1.0f;
#pragma unroll
        for (int i = 0; i < 4; ++i)
#pragma unroll
            for (int j = 0; j < 4; ++j)
#pragma unroll
                for (int r = 0; r < 4; ++r) {
                    int m = m0 + wm * 64 + i * 16 + g * 4 + r;   // token
                    int n = n0 + wn * 64 + j * 16 + c;           // feature
                    int b = m >> 11, tt = m & (T_ - 1);
                    int h = n >> 6, d = n & 63;
                    Out[((size_t)(b * H_ + h) * T_ + tt) * HD + d] = f2bf(acc[i][j][r] * os);
                }
    } else {
#pragma unroll
        for (int i = 0; i < 4; ++i)
#pragma unroll
            for (int j = 0; j < 4; ++j)
#pragma unroll
                for (int r = 0; r < 4; ++r) {
                    int m = m0 + wm * 64 + i * 16 + g * 4 + r;   // feature
                    int n = n0 + wn * 64 + j * 16 + c;           // token
                    int b = n >> 11, tt = n & (T_ - 1);
                    int h = m >> 6, d = m & 63;
                    Vt[((size_t)(b * H_ + h) * HD + d) * T_ + tt] = f2bf(acc[i][j][r]);
                }
    }
}

// Output projection: Y bf16 @ Wo^T + bo -> fp32 row-major. Grid (64,8). BK=64.
__global__ __launch_bounds__(256) void gemm_o(
    const short* __restrict__ Yb, const short* __restrict__ Wo,
    float* __restrict__ Out, const float* __restrict__ bias)
{
    const int K = 1024;
    __shared__ short As[128 * 64];
    __shared__ short Bs[128 * 64];
    const int t = threadIdx.x;
    const int w = t >> 6, l = t & 63, g = l >> 4, c = l & 15;
    const int wm = w & 1, wn = w >> 1;
    const int m0 = blockIdx.x * 128, n0 = blockIdx.y * 128;

    const int srow = l >> 3;
    const int sch = (l & 7) ^ (l >> 3);
    const int rch = c & 7;

    v4f acc[4][4];
#pragma unroll
    for (int i = 0; i < 4; ++i)
#pragma unroll
        for (int j = 0; j < 4; ++j) acc[i][j] = (v4f){0.f, 0.f, 0.f, 0.f};

    for (int k0 = 0; k0 < K; k0 += 64) {
        __syncthreads();
#pragma unroll
        for (int i = 0; i < 4; ++i) {
            int sp = w * 4 + i;
            gload_lds16(Yb + (size_t)(m0 + sp * 8 + srow) * K + k0 + sch * 8,
                        &As[sp * 512]);
            gload_lds16(Wo + (size_t)(n0 + sp * 8 + srow) * K + k0 + sch * 8,
                        &Bs[sp * 512]);
        }
        __syncthreads();
#pragma unroll
        for (int s = 0; s < 2; ++s) {
            const int kch = ((4 * s + g) ^ rch) * 8;
            bf16x8 af[4], bfr[4];
#pragma unroll
            for (int i = 0; i < 4; ++i)
                af[i] = *(const bf16x8*)&As[(wm * 64 + i * 16 + c) * 64 + kch];
#pragma unroll
            for (int j = 0; j < 4; ++j)
                bfr[j] = *(const bf16x8*)&Bs[(wn * 64 + j * 16 + c) * 64 + kch];
#pragma unroll
            for (int i = 0; i < 4; ++i)
#pragma unroll
                for (int j = 0; j < 4; ++j)
                    acc[i][j] = __builtin_amdgcn_mfma_f32_16x16x32_bf16(af[i], bfr[j], acc[i][j], 0, 0, 0);
        }
    }
#pragma unroll
    for (int i = 0; i < 4; ++i)
#pragma unroll
        for (int j = 0; j < 4; ++j)
#pragma unroll
            for (int r = 0; r < 4; ++r) {
                int m = m0 + wm * 64 + i * 16 + g * 4 + r;
                int n = n0 + wn * 64 + j * 16 + c;
                Out[(size_t)m * C_ + n] = acc[i][j][r] + bias[n];
            }
}

// Flash attention, causal, no-rescale softmax (Q pre-scaled by log2(e)/8).
// Q,K: (B,H,T,64) bf16; Vt: (B,H,64,T) bf16; Y: (B,T,C) bf16.
// Swapped QK^T keeps P fully in-register; Ks XOR-swizzled (conflicts=0).
// MERGED q-tile pair {qtL=p, qtH=31-p}, fused PV (V-frag read once feeds
// both tiles — R6 win).
//
// R8: PERMUTED-CONTIGUOUS V layout. The old pad-72 [dcol][key] layout made
// each PV fragment 2x ds_read_b64 with c/c+8 bank aliasing (R5: 8.65M
// conflict cycles; R6 halved the reads, conflicts remained on the rest).
// New: Vp[dcol][chunk][u*4+v] = V^T[dcol][32s+16u+4g+v], chunk=(4s+g)^(dcol&7),
// 64 shorts (128B) per dcol row. Lane (c,g) for (d,s) reads ONE b128 at
// (d*16+c)*64 + ((4s+g)^(c&7))*8 — identical bank pattern to the Ks frag
// read (8 lanes/16B-start, distinct rows) which measures ZERO conflicts.
// Register order t=u*4+v matches the P-slot key order exactly.
// Write side: each staged bf16x8 (keys 8*c0..8*c0+7, where s=c0>>2,
// u=(c0>>1)&1, g={2c0&3, (2c0+1)&3}, v=e&3) splits into 2x ds_write_b64.
__global__ __launch_bounds__(256) void attn_kernel(
    const short* __restrict__ Q, const short* __restrict__ Kp,
    const short* __restrict__ Vt, short* __restrict__ Y)
{
    __shared__ short Ks[2 * 64 * 32];    // [dim-half][key][32] via gll (swizzled)
    __shared__ short Vp[64 * 64];        // permuted V, 128B per dcol row
    const int t = threadIdx.x;
    const int w = t >> 6, l = t & 63, g = l >> 4, c = l & 15;
    const int bid = blockIdx.x;          // 1024 blocks
    const int slot = bid >> 3;
    const int p = slot & 15;
    const size_t bh = (size_t)((bid & 7) * 8 + (slot >> 4));  // XCD-local bh

    const int srow = l >> 2;
    const int sch = (l & 3) ^ ((l >> 3) & 3);
    const int gs = (g ^ ((c >> 1) & 3)) * 8;
    const int rch7 = c & 7;

    bf16x8 ones;
#pragma unroll
    for (int i = 0; i < 8; ++i) ones[i] = (short)0x3F80;  // bf16 1.0

    const int qtL = p, qtH = 31 - p;     // qtL <= 15 < 16 <= qtH always
    const int qbL = qtL * 64, qbH = qtH * 64;

    bf16x8 qL0, qL1, qH0, qH1;   // pre-scaled Q fragments (q = qb + w*16 + c)
    {
        const short* qp = &Q[(bh * T_ + qbL + w * 16 + c) * HD + g * 8];
        qL0 = *(const bf16x8*)qp;
        qL1 = *(const bf16x8*)(qp + 32);
    }
    {
        const short* qp = &Q[(bh * T_ + qbH + w * 16 + c) * HD + g * 8];
        qH0 = *(const bf16x8*)qp;
        qH1 = *(const bf16x8*)(qp + 32);
    }

    v4f OL[4], OH[4], accL, accH;
    accL = (v4f){0.f, 0.f, 0.f, 0.f};
    accH = (v4f){0.f, 0.f, 0.f, 0.f};
#pragma unroll
    for (int d = 0; d < 4; ++d) {
        OL[d] = (v4f){0.f, 0.f, 0.f, 0.f};
        OH[d] = (v4f){0.f, 0.f, 0.f, 0.f};
    }

    union pu { bf16x8 v; uint32_t u[4]; };

    for (int kb = 0; kb <= qtH; ++kb) {
        const int kbase = kb * 64;
        __syncthreads();
        // K tile via gll: 8 chunks (half,rowblk), 2 per wave, swizzled src
#pragma unroll
        for (int i = 0; i < 2; ++i) {
            int gi = w * 2 + i;
            int hk = gi >> 2, rb = gi & 3;
            const short* gp = &Kp[(bh * T_ + kbase + rb * 16 + srow) * HD + hk * 32 + sch * 8];
            gload_lds16(gp, &Ks[hk * 2048 + rb * 512]);
        }
        // V tile -> permuted layout: 2x ds_write_b64 per staged bf16x8
#pragma unroll
        for (int i = 0; i < 2; ++i) {
            int id = i * 256 + t;
            int rr = id >> 3, c0 = id & 7;
            union { bf16x8 v8; bf16x4 v4[2]; } vu;
            vu.v8 = *(const bf16x8*)&Vt[(bh * HD + rr) * T_ + kbase + c0 * 8];
            int ss = c0 >> 2, uu = (c0 >> 1) & 1;
            int base = rr * 64 + uu * 4;
            int ch1 = ((ss * 4 + ((2 * c0) & 3)) ^ (rr & 7)) * 8;
            int ch2 = ((ss * 4 + ((2 * c0 + 1) & 3)) ^ (rr & 7)) * 8;
            *(bf16x4*)&Vp[base + ch1] = vu.v4[0];
            *(bf16x4*)&Vp[base + ch2] = vu.v4[1];
        }
        __syncthreads();

        const bool doL = (kb <= qtL);   // wave-uniform

        // ---- QK^T high (kf frags read inline; transient regs) ----
        pu paH[2], paL[2];
        {
            float s2[4][4];
#pragma unroll
            for (int j = 0; j < 4; ++j) {
                bf16x8 kf0 = *(const bf16x8*)&Ks[(j * 16 + c) * 32 + gs];
                bf16x8 kf1 = *(const bf16x8*)&Ks[2048 + (j * 16 + c) * 32 + gs];
                v4f sa = (v4f){0.f, 0.f, 0.f, 0.f};
                sa = __builtin_amdgcn_mfma_f32_16x16x32_bf16(kf0, qH0, sa, 0, 0, 0);
                sa = __builtin_amdgcn_mfma_f32_16x16x32_bf16(kf1, qH1, sa, 0, 0, 0);
#pragma unroll
                for (int r = 0; r < 4; ++r) s2[j][r] = sa[r];
            }
            if (kb == qtH) {  // diagonal tile mask
                const int q = qbH + w * 16 + c;
#pragma unroll
                for (int j = 0; j < 4; ++j)
#pragma unroll
                    for (int r = 0; r < 4; ++r) {
                        int key = kbase + j * 16 + g * 4 + r;
                        if (key > q) s2[j][r] = -3.0e38f;
                    }
            }
#pragma unroll
            for (int s = 0; s < 2; ++s)
#pragma unroll
                for (int wi = 0; wi < 4; ++wi) {
                    int j = 2 * s + (wi >> 1);
                    int r0 = (wi & 1) * 2;
                    float x = __builtin_amdgcn_exp2f(s2[j][r0]);
                    float y = __builtin_amdgcn_exp2f(s2[j][r0 + 1]);
                    paH[s].u[wi] = pack2t(x, y);
                }
        }
        // ---- QK^T low (only while kb <= qtL) ----
        if (doL) {
            float s2[4][4];
#pragma unroll
            for (int j = 0; j < 4; ++j) {
                bf16x8 kf0 = *(const bf16x8*)&Ks[(j * 16 + c) * 32 + gs];
                bf16x8 kf1 = *(const bf16x8*)&Ks[2048 + (j * 16 + c) * 32 + gs];
                v4f sa = (v4f){0.f, 0.f, 0.f, 0.f};
                sa = __builtin_amdgcn_mfma_f32_16x16x32_bf16(kf0, qL0, sa, 0, 0, 0);
                sa = __builtin_amdgcn_mfma_f32_16x16x32_bf16(kf1, qL1, sa, 0, 0, 0);
#pragma unroll
                for (int r = 0; r < 4; ++r) s2[j][r] = sa[r];
            }
            if (kb == qtL) {  // diagonal tile mask
                const int q = qbL + w * 16 + c;
#pragma unroll
                for (int j = 0; j < 4; ++j)
#pragma unroll
                    for (int r = 0; r < 4; ++r) {
                        int key = kbase + j * 16 + g * 4 + r;
                        if (key > q) s2[j][r] = -3.0e38f;
                    }
            }
#pragma unroll
            for (int s = 0; s < 2; ++s)
#pragma unroll
                for (int wi = 0; wi < 4; ++wi) {
                    int j = 2 * s + (wi >> 1);
                    int r0 = (wi & 1) * 2;
                    float x = __builtin_amdgcn_exp2f(s2[j][r0]);
                    float y = __builtin_amdgcn_exp2f(s2[j][r0 + 1]);
                    paL[s].u[wi] = pack2t(x, y);
                }
            // ---- FUSED PV: one b128 V-read feeds both tiles ----
#pragma unroll
            for (int s = 0; s < 2; ++s) {
                const int vch = ((s * 4 + g) ^ rch7) * 8;
#pragma unroll
                for (int d = 0; d < 4; ++d) {
                    bf16x8 vf = *(const bf16x8*)&Vp[(d * 16 + c) * 64 + vch];
                    OH[d] = __builtin_amdgcn_mfma_f32_16x16x32_bf16(paH[s].v, vf, OH[d], 0, 0, 0);
                    OL[d] = __builtin_amdgcn_mfma_f32_16x16x32_bf16(paL[s].v, vf, OL[d], 0, 0, 0);
                }
                accH = __builtin_amdgcn_mfma_f32_16x16x32_bf16(paH[s].v, ones, accH, 0, 0, 0);
                accL = __builtin_amdgcn_mfma_f32_16x16x32_bf16(paL[s].v, ones, accL, 0, 0, 0);
            }
        } else {
            // ---- PV high only ----
#pragma unroll
            for (int s = 0; s < 2; ++s) {
                const int vch = ((s * 4 + g) ^ rch7) * 8;
#pragma unroll
                for (int d = 0; d < 4; ++d) {
                    bf16x8 vf = *(const bf16x8*)&Vp[(d * 16 + c) * 64 + vch];
                    OH[d] = __builtin_amdgcn_mfma_f32_16x16x32_bf16(paH[s].v, vf, OH[d], 0, 0, 0);
                }
                accH = __builtin_amdgcn_mfma_f32_16x16x32_bf16(paH[s].v, ones, accH, 0, 0, 0);
            }
        }
    }
    // D: row = q = qb+w*16+g*4+r, col = c (d-dim)
#pragma unroll
    for (int r = 0; r < 4; ++r) {
        float rlL = 1.0f / accL[r];
        float rlH = 1.0f / accH[r];
        size_t baseoff = ((size_t)(bh >> 4) * T_ + w * 16 + g * 4 + r) * C_ + (bh & 15) * HD;
        size_t offL = baseoff + (size_t)qbL * C_;
        size_t offH = baseoff + (size_t)qbH * C_;
#pragma unroll
        for (int d = 0; d < 4; ++d) {
            Y[offL + d * 16 + c] = f2bf(OL[d][r] * rlL);
            Y[offH + d * 16 + c] = f2bf(OH[d][r] * rlH);
        }
    }
}

extern "C" void kernel_launch(void* const* d_in, const int* in_sizes, int n_in,
                              void* d_out, int out_size, void* d_ws, size_t ws_size,
                              hipStream_t stream) {
    const float* xq = (const float*)d_in[0];
    const float* xk = (const float*)d_in[1];
    const float* xv = (const float*)d_in[2];
    const float* Wq = (const float*)d_in[3];
    const float* Wk = (const float*)d_in[4];
    const float* Wv = (const float*)d_in[5];
    const float* Wo = (const float*)d_in[6];
    const float* bo = (const float*)d_in[7];

    const size_t NE = (size_t)B_ * H_ * T_ * HD;   // 8.4M elems (16MB bf16)
    const size_t WE = (size_t)C_ * C_;             // 1M elems
    short* Qh    = (short*)d_ws;
    short* Kh    = Qh + NE;
    short* slotA = Kh + NE;       // xq_bf -> (after proj) Y
    short* slotB = slotA + NE;    // xk_bf
    short* Wbf   = slotB + NE;    // 4 x 2MB; total ws = 72MB
    short* Vt    = (short*)d_out; // scratch: dead until gemm_o overwrites d_out

    const float qscale = 0.18033688011112042f;     // log2(e)/sqrt(64)
    dim3 blk(256);

    hipLaunchKernelGGL(convx, dim3(10240), blk, 0, stream,
                       xq, xk, slotA, slotB, Wq, Wk, Wv, Wo, Wbf);
    hipLaunchKernelGGL(proj_gemm, dim3(64, 8, 3), blk, 0, stream,
                       slotA, slotB, Wbf, xv, Qh, Kh, Vt, qscale);
    hipLaunchKernelGGL(attn_kernel, dim3(B_ * H_ * (T_ / 128)), blk, 0, stream,
                       Qh, Kh, Vt, slotA);
    hipLaunchKernelGGL(gemm_o, dim3(64, 8), blk, 0, stream,
                       slotA, Wbf + 3 * WE, (float*)d_out, bo);
}